// Round 2
// baseline (245.726 us; speedup 1.0000x reference)
//
#include <hip/hip_runtime.h>
#include <math.h>

// Problem constants (fixed by reference setup_inputs).
constexpr int B = 16, C = 4, H = 768, W = 768;
constexpr int HW = H * W;                 // 589824 pixels per (b, channel)
constexpr int G_PER_B = HW / 4;           // 147456 float4-groups per channel
constexpr int CHUNKS = 128;               // chunks per batch image
constexpr int G_PER_CHUNK = G_PER_B / CHUNKS; // 1152
constexpr float LN2 = 0.6931471805599453f;
constexpr float L2E = 1.4426950408889634f;
constexpr float EULER = 2.71828182845904523536f;

// Main streaming kernel: per-pixel 4-class log-softmax at the target class
// (dp_loss numerator) + 4-class argmax counts (p_pred_num).
// Accumulate per (b, c): dp_sum[b][c] = sum_{tgt==c} (lse - x_c)
//                        cnt[b][c]    = #{argmax == c}
__global__ __launch_bounds__(256) void dp_main_kernel(
    const float* __restrict__ net,      // (B, C, H, W)
    const int* __restrict__ target,     // (B, 1, H, W)
    float* __restrict__ gdp,            // (B*C) global dp sums
    int* __restrict__ gcnt)             // (B*C) global argmax counts
{
    const int b = blockIdx.x / CHUNKS;
    const int chunk = blockIdx.x % CHUNKS;

    const float4* __restrict__ n4 = (const float4*)(net + (size_t)b * C * HW);
    const int4* __restrict__ t4 = (const int4*)(target + (size_t)b * HW);

    // Named per-class accumulators (no runtime-indexed arrays -> stay in VGPRs)
    float dp0 = 0.f, dp1 = 0.f, dp2 = 0.f, dp3 = 0.f;
    int c0 = 0, c1 = 0, c2 = 0, c3 = 0;

    __shared__ float sdp[C];
    __shared__ int scnt[C];
    if (threadIdx.x < C) { sdp[threadIdx.x] = 0.f; scnt[threadIdx.x] = 0; }
    __syncthreads();

    const int base = chunk * G_PER_CHUNK;
    for (int i = threadIdx.x; i < G_PER_CHUNK; i += 256) {
        const int g = base + i;
        // 4 channels x 4 consecutive pixels: fully coalesced 16B lane loads
        const float4 a0 = n4[g];
        const float4 a1 = n4[g + G_PER_B];
        const float4 a2 = n4[g + 2 * G_PER_B];
        const float4 a3 = n4[g + 3 * G_PER_B];
        const int4 tv = t4[g];

        const float X0[4] = {a0.x, a0.y, a0.z, a0.w};
        const float X1[4] = {a1.x, a1.y, a1.z, a1.w};
        const float X2[4] = {a2.x, a2.y, a2.z, a2.w};
        const float X3[4] = {a3.x, a3.y, a3.z, a3.w};
        const int   T[4]  = {tv.x, tv.y, tv.z, tv.w};

#pragma unroll
        for (int j = 0; j < 4; ++j) {
            const float x0 = X0[j], x1 = X1[j], x2 = X2[j], x3 = X3[j];
            const int t = T[j];

            // first-occurrence argmax (jnp.argmax semantics: strict >)
            float m = x0; int am = 0;
            if (x1 > m) { m = x1; am = 1; }
            if (x2 > m) { m = x2; am = 2; }
            if (x3 > m) { m = x3; am = 3; }

            // logsumexp via hw v_exp_f32/v_log_f32 (exp2/log2 forms)
            const float s = exp2f((x0 - m) * L2E) + exp2f((x1 - m) * L2E)
                          + exp2f((x2 - m) * L2E) + exp2f((x3 - m) * L2E);
            const float lse = m + log2f(s) * LN2;

            const float xt = (t == 0) ? x0 : (t == 1) ? x1 : (t == 2) ? x2 : x3;
            const float val = lse - xt;   // -log_softmax at the target class

            dp0 += (t == 0) ? val : 0.f;
            dp1 += (t == 1) ? val : 0.f;
            dp2 += (t == 2) ? val : 0.f;
            dp3 += (t == 3) ? val : 0.f;
            c0 += (am == 0);
            c1 += (am == 1);
            c2 += (am == 2);
            c3 += (am == 3);
        }
    }

    // wave(64)-level butterfly reduce of all 8 accumulators
#pragma unroll
    for (int off = 32; off > 0; off >>= 1) {
        dp0 += __shfl_down(dp0, off);
        dp1 += __shfl_down(dp1, off);
        dp2 += __shfl_down(dp2, off);
        dp3 += __shfl_down(dp3, off);
        c0 += __shfl_down(c0, off);
        c1 += __shfl_down(c1, off);
        c2 += __shfl_down(c2, off);
        c3 += __shfl_down(c3, off);
    }

    if ((threadIdx.x & 63) == 0) {   // one leader per wave (4 waves/block)
        atomicAdd(&sdp[0], dp0); atomicAdd(&sdp[1], dp1);
        atomicAdd(&sdp[2], dp2); atomicAdd(&sdp[3], dp3);
        atomicAdd(&scnt[0], c0); atomicAdd(&scnt[1], c1);
        atomicAdd(&scnt[2], c2); atomicAdd(&scnt[3], c3);
    }
    __syncthreads();

    if (threadIdx.x < C) {
        atomicAdd(&gdp[b * C + threadIdx.x], sdp[threadIdx.x]);
        atomicAdd(&gcnt[b * C + threadIdx.x], scnt[threadIdx.x]);
    }
}

// Finalize: 64 lanes <-> the 64 (b,c) cells. Computes normalized weights and
// the scalar result = sum_{b, c>=1} w * (dp_sum - cnt) / HW.
__global__ __launch_bounds__(64) void dp_finalize_kernel(
    const float* __restrict__ gdp,
    const int* __restrict__ gcnt,
    const float* __restrict__ bw,     // (B, C) bare_weight
    float* __restrict__ out)
{
    const int lane = threadIdx.x;     // b = lane>>2, c = lane&3
    const int c = lane & 3;

    const float s = 1.0f / (1.0f + expf(-bw[lane]));  // sigmoid

    // column (per-class) mean over b: xor-reduce over the b bits (4,8,16,32)
    float colsum = s;
#pragma unroll
    for (int off = 4; off < 64; off <<= 1) colsum += __shfl_xor(colsum, off);
    const float colmean = colsum * (1.0f / (float)B);

    // fixed_w: gt_ids == 0 always (argmax over singleton axis), so
    // gt_num[b,0] = HW, gt_num[b,c>0] = 0.
    const float fixed_w = (c == 0) ? (logf((float)HW + EULER) + EULER)
                                   : (1.0f + EULER);
    const float w = s / colmean / fixed_w;

    float term = 0.f;
    if (c >= 1) {
        term = w * (gdp[lane] - (float)gcnt[lane]) * (1.0f / (float)HW);
    }
#pragma unroll
    for (int off = 1; off < 64; off <<= 1) term += __shfl_xor(term, off);

    if (lane == 0) out[0] = term;
}

extern "C" void kernel_launch(void* const* d_in, const int* in_sizes, int n_in,
                              void* d_out, int out_size, void* d_ws, size_t ws_size,
                              hipStream_t stream) {
    const float* net = (const float*)d_in[0];
    const int* target = (const int*)d_in[1];
    const float* bw = (const float*)d_in[2];
    float* out = (float*)d_out;

    float* gdp = (float*)d_ws;
    int* gcnt = (int*)((char*)d_ws + B * C * sizeof(float));

    // d_ws is poisoned 0xAA before every timed call -> zero the accumulators
    hipMemsetAsync(d_ws, 0, B * C * (sizeof(float) + sizeof(int)), stream);

    dp_main_kernel<<<B * CHUNKS, 256, 0, stream>>>(net, target, gdp, gcnt);
    dp_finalize_kernel<<<1, 64, 0, stream>>>(gdp, gcnt, bw, out);
}